// Round 5
// baseline (674.939 us; speedup 1.0000x reference)
//
#include <hip/hip_runtime.h>

// MoE switch layer: B=8, N=2048, D=1024, E=8, DFF=4096, CAP=320
#define Bq 8
#define Nq 2048
#define Dq 1024
#define Eq 8
#define DFFq 4096
#define CAPq 320
#define Mq (Bq * CAPq)   // 2560 rows per expert
#define Tq (Bq * Nq)     // 16384 tokens

typedef __attribute__((ext_vector_type(8))) short bf16x8;
typedef __attribute__((ext_vector_type(4))) float f32x4;

static __device__ __forceinline__ unsigned short f2bf(float f) {
    union { float f; unsigned u; } v;
    v.f = f;
    unsigned r = v.u + 0x7fffu + ((v.u >> 16) & 1u);   // RNE
    return (unsigned short)(r >> 16);
}

static __device__ __forceinline__ void gload_lds16(const void* g, void* l) {
    __builtin_amdgcn_global_load_lds(
        (const __attribute__((address_space(1))) unsigned int*)g,
        (__attribute__((address_space(3))) unsigned int*)l, 16, 0, 0);
}

// ---------------- routing: logits -> softmax -> argmax/gate ----------------
__global__ __launch_bounds__(256) void route_kernel(
    const float* __restrict__ tok, const float* __restrict__ Wg,
    int* __restrict__ eidx, float* __restrict__ gate)
{
    int wv = threadIdx.x >> 6, lane = threadIdx.x & 63;
    int t = blockIdx.x * 4 + wv;
    const float* tp = tok + (size_t)t * Dq;
    float acc[8] = {0.f,0.f,0.f,0.f,0.f,0.f,0.f,0.f};
    for (int it = 0; it < Dq / 64; ++it) {
        int d = it * 64 + lane;
        float x = tp[d];
        const float4* w = (const float4*)(Wg + (size_t)d * 8);
        float4 w0 = w[0], w1 = w[1];
        acc[0] += x * w0.x; acc[1] += x * w0.y; acc[2] += x * w0.z; acc[3] += x * w0.w;
        acc[4] += x * w1.x; acc[5] += x * w1.y; acc[6] += x * w1.z; acc[7] += x * w1.w;
    }
#pragma unroll
    for (int e = 0; e < 8; ++e)
#pragma unroll
        for (int off = 32; off; off >>= 1)
            acc[e] += __shfl_xor(acc[e], off, 64);
    if (lane == 0) {
        float m = acc[0]; int bi = 0;
#pragma unroll
        for (int e = 1; e < 8; ++e) if (acc[e] > m) { m = acc[e]; bi = e; }
        float s = 0.f;
#pragma unroll
        for (int e = 0; e < 8; ++e) s += expf(acc[e] - m);
        eidx[t] = bi;
        gate[t] = 1.0f / s;   // max prob
    }
}

// ------------- slot assignment: cumsum-order scan per (b,e) ----------------
__global__ __launch_bounds__(64) void slot_kernel(
    const int* __restrict__ eidx, int* __restrict__ tfs)
{
    int b = blockIdx.x >> 3, e = blockIdx.x & 7;
    int lane = threadIdx.x;
    const int* ip = eidx + (size_t)b * Nq;
    int base = (e * Bq + b) * CAPq;
    int cnt = 0;
    for (int it = 0; it < Nq / 64; ++it) {
        int n = it * 64 + lane;
        bool my = (ip[n] == e);
        unsigned long long mask = __ballot(my);
        if (my) {
            int pos = cnt + __popcll(mask & ((1ull << lane) - 1ull));
            if (pos < CAPq) tfs[base + pos] = b * Nq + n;
        }
        cnt += __popcll(mask);
    }
}

// ------------- dispatch: gather token rows -> bf16 expert buffers ----------
__global__ __launch_bounds__(128) void dispatch_kernel(
    const float* __restrict__ tok, const int* __restrict__ tfs,
    unsigned short* __restrict__ X)
{
    int r = blockIdx.x;          // 0 .. E*B*CAP-1
    int t = tfs[r];
    int d0 = threadIdx.x * 8;
    unsigned short o[8];
    if (t < 0) {
#pragma unroll
        for (int k = 0; k < 8; ++k) o[k] = 0;
    } else {
        const float4* p = (const float4*)(tok + (size_t)t * Dq + d0);
        float4 a = p[0], b = p[1];
        o[0]=f2bf(a.x); o[1]=f2bf(a.y); o[2]=f2bf(a.z); o[3]=f2bf(a.w);
        o[4]=f2bf(b.x); o[5]=f2bf(b.y); o[6]=f2bf(b.z); o[7]=f2bf(b.w);
    }
    *(uint4*)(X + (size_t)r * Dq + d0) = *(const uint4*)o;
}

// ------- weight transpose+convert: in [E][R][C] f32 -> out [E][C][R] bf16 --
__global__ __launch_bounds__(256) void transpose_cvt(
    const float* __restrict__ in, unsigned short* __restrict__ out,
    int R, int C)
{
    __shared__ float tile[32][33];
    int e = blockIdx.z;
    int c0 = blockIdx.x * 32, r0 = blockIdx.y * 32;
    int tx = threadIdx.x & 31, ty = threadIdx.x >> 5;
    const float* ip = in + (size_t)e * R * C;
#pragma unroll
    for (int rr = 0; rr < 4; ++rr)
        tile[ty + rr * 8][tx] = ip[(size_t)(r0 + ty + rr * 8) * C + c0 + tx];
    __syncthreads();
    unsigned short* op = out + (size_t)e * R * C;
#pragma unroll
    for (int rr = 0; rr < 4; ++rr)
        op[(size_t)(c0 + ty + rr * 8) * R + r0 + tx] = f2bf(tile[tx][ty + rr * 8]);
}

// ============ 256x128 NT GEMM, BK=32, 4 waves, 2 blocks/CU ================
// C[M][N] = A[M][K] * Bt[N][K]^T per expert. Per-wave 128x64 (2M x 2N waves).
// Double-buffered LDS (50 KB -> 2 blocks/CU for cross-block pipe overlap).
// Pipeline: stage(k+1) issued at iter top; vmcnt(0) AFTER ~1242cyc of compute
// (issue-to-wait gap > HBM latency -> wait ~free); ONE raw barrier per K-tile.
// LDS swizzle: chunk ^= (row>>1)&3 (2-way bank aliasing = free, m136);
// pre-swizzled global source + linear gload_lds dest (rule 21).
// MODE 0: H = relu(C) bf16.  MODE 1: scatter rows to Out with gate.
template <int MODE, int Ndim, int Kdim>
__global__ __launch_bounds__(256, 2) void gemmk(
    const unsigned short* __restrict__ A,   // [E][M][K] bf16
    const unsigned short* __restrict__ Bt,  // [E][N][K] bf16
    unsigned short* __restrict__ Hout,      // [E][M][N] bf16  (MODE 0)
    float* __restrict__ Out,                // [T][D] f32      (MODE 1)
    const int* __restrict__ tfs,            // [E][M]
    const float* __restrict__ gate)         // [T]
{
    constexpr int NK  = Kdim / 32;
    constexpr int NTB = Ndim / 128;
    constexpr int MT  = Mq / 256;            // 10
    constexpr int NWG = MT * NTB * Eq;       // multiple of 8

    __shared__ __align__(16) unsigned short As[2][256 * 32];  // 32 KiB
    __shared__ __align__(16) unsigned short Bs[2][128 * 32];  // 16 KiB
    __shared__ int   t_lds[256];
    __shared__ float g_lds[256];

    // XCD-aware bijective swizzle (NWG % 8 == 0)
    int flat = blockIdx.x;
    int wg = (flat & 7) * (NWG / 8) + (flat >> 3);
    int e   = wg / (MT * NTB);
    int rem = wg - e * (MT * NTB);
    int mb = rem / NTB, nb = rem - mb * NTB;
    int m0 = mb * 256, n0 = nb * 128;

    const char* Ae = (const char*)(A  + (size_t)e * Mq * Kdim + (size_t)m0 * Kdim);
    const char* Be = (const char*)(Bt + (size_t)e * Ndim * Kdim + (size_t)n0 * Kdim);

    const int tid = threadIdx.x;
    if (MODE == 1) {
        int t = tfs[e * Mq + m0 + tid];
        t_lds[tid] = t;
        g_lds[tid] = (t >= 0) ? gate[t] : 0.f;
    }

    const int ln = tid & 63;
    const int wv = tid >> 6;
    const int wr = wv >> 1, wc = wv & 1;       // 2M x 2N waves, per-wave 128x64
    const int lrow = ln & 15;
    const int lk = ln >> 4;                    // k-chunk 0..3 (8 bf16 each)
    const int cswz = ((lk ^ ((lrow >> 1) & 3)) << 4);   // read-side swizzle (bytes)
    const int ardo = wr * 8192 + lrow * 64 + cswz;      // A frag base in buffer
    const int brdo = wc * 4096 + lrow * 64 + cswz;      // B frag base in buffer

    // staging: rows of 64B; thread covers row (wv*64 + i*16 + ln>>2), chunk ln&3
    const int schunk = (((ln & 3) ^ ((ln >> 3) & 3)) << 4);  // pre-swizzled src chunk
    const size_t Kb = (size_t)Kdim * 2;                       // global row stride
    const char* gAs = Ae + (size_t)(wv * 64 + (ln >> 2)) * Kb + schunk;
    const char* gBs = Be + (size_t)(wv * 32 + (ln >> 2)) * Kb + schunk;
    char* lAs = (char*)As + wv * 4096 + ln * 16;
    char* lBs = (char*)Bs + wv * 2048 + ln * 16;

    #define STG(kt, buf) {                                               \
        const size_t _ko = (size_t)(kt) * 64;                            \
        gload_lds16(gAs + _ko,               lAs + (buf) * 16384);       \
        gload_lds16(gAs + 16 * Kb + _ko,     lAs + (buf) * 16384 + 1024);\
        gload_lds16(gAs + 32 * Kb + _ko,     lAs + (buf) * 16384 + 2048);\
        gload_lds16(gAs + 48 * Kb + _ko,     lAs + (buf) * 16384 + 3072);\
        gload_lds16(gBs + _ko,               lBs + (buf) * 8192);        \
        gload_lds16(gBs + 16 * Kb + _ko,     lBs + (buf) * 8192 + 1024); }

    f32x4 acc[8][4] = {};

    // prologue
    STG(0, 0);
    asm volatile("s_waitcnt vmcnt(0) lgkmcnt(0)");
    __builtin_amdgcn_s_barrier();
    __builtin_amdgcn_sched_barrier(0);

    for (int k = 0; k < NK; ++k) {
        const int buf = k & 1;
        if (k + 1 < NK) STG(k + 1, buf ^ 1);
        const char* pa = (const char*)As + buf * 16384;
        const char* pb = (const char*)Bs + buf * 8192;
        bf16x8 aq[8], bq[4];
#pragma unroll
        for (int fr = 0; fr < 8; ++fr)
            aq[fr] = *(const bf16x8*)(pa + ardo + fr * 1024);
#pragma unroll
        for (int br = 0; br < 4; ++br)
            bq[br] = *(const bf16x8*)(pb + brdo + br * 1024);
        __builtin_amdgcn_s_setprio(1);
#pragma unroll
        for (int fr = 0; fr < 8; ++fr)
#pragma unroll
            for (int br = 0; br < 4; ++br)
                acc[fr][br] = __builtin_amdgcn_mfma_f32_16x16x32_bf16(
                    aq[fr], bq[br], acc[fr][br], 0, 0, 0);
        __builtin_amdgcn_s_setprio(0);
        asm volatile("s_waitcnt vmcnt(0)");   // stage(k+1) issued ~1 K-tile ago
        __builtin_amdgcn_s_barrier();
        __builtin_amdgcn_sched_barrier(0);
    }

    // -------------------------------- epilogue --------------------------------
    if (MODE == 0) {
        unsigned short* Hp = Hout + (size_t)e * Mq * Ndim;
#pragma unroll
        for (int fr = 0; fr < 8; ++fr) {
            int row = m0 + wr * 128 + fr * 16 + lk * 4;
#pragma unroll
            for (int br = 0; br < 4; ++br) {
                int col = n0 + wc * 64 + br * 16 + lrow;
#pragma unroll
                for (int r = 0; r < 4; ++r)
                    Hp[(size_t)(row + r) * Ndim + col] =
                        f2bf(fmaxf(acc[fr][br][r], 0.f));
            }
        }
    } else {
#pragma unroll
        for (int fr = 0; fr < 8; ++fr) {
            int rl = wr * 128 + fr * 16 + lk * 4;
#pragma unroll
            for (int r = 0; r < 4; ++r) {
                int tt = t_lds[rl + r];
                if (tt < 0) continue;
                float g = g_lds[rl + r];
#pragma unroll
                for (int br = 0; br < 4; ++br) {
                    int col = n0 + wc * 64 + br * 16 + lrow;
                    Out[(size_t)tt * Dq + col] = g * acc[fr][br][r];
                }
            }
        }
    }
    #undef STG
}

// ---------------------------------------------------------------------------
extern "C" void kernel_launch(void* const* d_in, const int* in_sizes, int n_in,
                              void* d_out, int out_size, void* d_ws, size_t ws_size,
                              hipStream_t stream)
{
    const float* tok = (const float*)d_in[0];
    const float* Wg  = (const float*)d_in[1];
    const float* W1  = (const float*)d_in[2];
    const float* W2  = (const float*)d_in[3];
    float* out = (float*)d_out;
    char* ws = (char*)d_ws;

    // workspace layout (bytes)
    unsigned short* W1T = (unsigned short*)(ws);                    // [E][DFF][D] bf16  67108864
    unsigned short* W2T = (unsigned short*)(ws + 67108864);         // [E][D][DFF] bf16  67108864
    unsigned short* X   = (unsigned short*)(ws + 134217728);        // [E][M][D]  bf16   41943040
    unsigned short* H   = (unsigned short*)(ws + 176160768);        // [E][M][DFF] bf16 167772160
    int*   tfs  = (int*)(ws + 343932928);                           // [E][M]            81920
    int*   eidx = (int*)(ws + 344014848);                           // [T]               65536
    float* gate = (float*)(ws + 344080384);                         // [T]               65536

    hipMemsetAsync(d_out, 0, (size_t)out_size * 4, stream);
    hipMemsetAsync(tfs, 0xFF, Eq * Mq * 4, stream);

    route_kernel<<<Tq / 4, 256, 0, stream>>>(tok, Wg, eidx, gate);
    slot_kernel<<<Bq * Eq, 64, 0, stream>>>(eidx, tfs);
    dispatch_kernel<<<Eq * Mq, 128, 0, stream>>>(tok, tfs, X);
    transpose_cvt<<<dim3(DFFq / 32, Dq / 32, Eq), 256, 0, stream>>>(W1, W1T, Dq, DFFq);
    transpose_cvt<<<dim3(Dq / 32, DFFq / 32, Eq), 256, 0, stream>>>(W2, W2T, DFFq, Dq);

    // GEMM1: H = relu(X @ W1): 10 x 32 x 8 = 2560 blocks = 5 exact rounds @2/CU
    gemmk<0, DFFq, Dq><<<(Mq / 256) * (DFFq / 128) * Eq, 256, 0, stream>>>(
        X, W1T, H, nullptr, nullptr, nullptr);
    // GEMM2: out[token] = gate * (H @ W2): 10 x 8 x 8 = 640 blocks
    gemmk<1, Dq, DFFq><<<(Mq / 256) * (Dq / 128) * Eq, 256, 0, stream>>>(
        H, W2T, nullptr, out, tfs, gate);
}